// Round 3
// baseline (382.830 us; speedup 1.0000x reference)
//
#include <hip/hip_runtime.h>
#include <hip/hip_bf16.h>

#define B_    16
#define CIN_  256
#define COUT_ 3
#define WDIM_ 512
#define H_    128
#define HW_   (H_*H_)     // 16384
#define OH_   256

// -------- Kernel 1: styles + modulated 1x1 weights --------
// mw[b][i] = float4( k[0,i]*st, k[1,i]*st, k[2,i]*st, 0 )
// st = (dot(w[b,:], aw[i,:]) / sqrt(512) + ab[i]) / 16
__global__ __launch_bounds__(64) void k_styles(const float* __restrict__ w,
    const float* __restrict__ aw, const float* __restrict__ ab,
    const float* __restrict__ cw, float* __restrict__ mw)
{
    int bi = blockIdx.x;            // b*256 + i
    int b = bi >> 8, i = bi & 255;
    int lane = threadIdx.x;
    const float* wr = w + b * WDIM_;
    const float* ar = aw + (size_t)i * WDIM_;
    float s = 0.f;
    #pragma unroll
    for (int t = 0; t < 8; ++t) s += wr[lane + 64*t] * ar[lane + 64*t];
    #pragma unroll
    for (int off = 32; off > 0; off >>= 1) s += __shfl_down(s, off);
    if (lane == 0) {
        float st = (s * 0.04419417382415922f + ab[i]) * 0.0625f; // 1/sqrt(512), 1/sqrt(256)
        float4 v;
        v.x = cw[i]          * st;
        v.y = cw[CIN_ + i]   * st;
        v.z = cw[2*CIN_ + i] * st;
        v.w = 0.f;
        reinterpret_cast<float4*>(mw)[bi] = v;
    }
}

// -------- Kernel 2: modulated 1x1 conv + bias + clamp --------
// y[b][o][hw] = clamp(sum_i x[b][i][hw]*mw[b][i][o] + cb[o], +-256)
// grid = B*32 blocks, 256 thr, 2 px/thread (float2 loads, 512B/wave coalesced)
__global__ __launch_bounds__(256) void k_conv(const float* __restrict__ x,
    const float* __restrict__ mw, const float* __restrict__ cb,
    float* __restrict__ y)
{
    int b    = blockIdx.x >> 5;
    int base = ((blockIdx.x & 31) << 9) + (threadIdx.x << 1);
    const float2* xp  = reinterpret_cast<const float2*>(x + (size_t)b * CIN_ * HW_ + base);
    const float4* mwp = reinterpret_cast<const float4*>(mw) + b * CIN_;
    float a0x=0.f,a0y=0.f,a1x=0.f,a1y=0.f,a2x=0.f,a2y=0.f;
    #pragma unroll 8
    for (int i = 0; i < CIN_; ++i) {
        float2 xv = xp[(size_t)i * (HW_/2)];
        float4 m  = mwp[i];
        a0x += xv.x*m.x; a0y += xv.y*m.x;
        a1x += xv.x*m.y; a1y += xv.y*m.y;
        a2x += xv.x*m.z; a2y += xv.y*m.z;
    }
    float b0 = cb[0], b1 = cb[1], b2 = cb[2];
    auto cl = [](float v){ return fminf(fmaxf(v, -256.f), 256.f); };
    float* yp = y + (size_t)b * COUT_ * HW_ + base;
    *reinterpret_cast<float2*>(yp)          = make_float2(cl(a0x+b0), cl(a0y+b0));
    *reinterpret_cast<float2*>(yp +   HW_)  = make_float2(cl(a1x+b1), cl(a1y+b1));
    *reinterpret_cast<float2*>(yp + 2*HW_)  = make_float2(cl(a2x+b2), cl(a2y+b2));
}

// -------- Kernel 3: horizontal polyphase upsample (x2, 13-tap) --------
// even out o=2q : sum_{j=0..5} y[q-3+j] * f[11-2j] * 2
// odd  out o=2q+1: sum_{j=0..6} y[q-3+j] * f[12-2j] * 2
__global__ __launch_bounds__(256) void k_upx(const float* __restrict__ y,
    const float* __restrict__ f, float* __restrict__ t)
{
    int idx = blockIdx.x * 256 + threadIdx.x;   // over (B*3*128) rows * 128 q
    int q   = idx & 127;
    int row = idx >> 7;                          // plane*128 + h
    const float* yr = y + (size_t)row * H_;
    int i0 = q - 3;
    float v[7];
    #pragma unroll
    for (int j = 0; j < 7; ++j) {
        int i = i0 + j;
        v[j] = (i >= 0 && i < H_) ? yr[i] : 0.f;
    }
    float e = 0.f, o = 0.f;
    #pragma unroll
    for (int j = 0; j < 6; ++j) e += v[j] * f[11 - 2*j];
    #pragma unroll
    for (int j = 0; j < 7; ++j) o += v[j] * f[12 - 2*j];
    reinterpret_cast<float2*>(t + (size_t)row * OH_)[q] = make_float2(e * 2.f, o * 2.f);
}

// -------- Kernel 4: vertical polyphase upsample, fp32 store --------
// thread handles 2 cols (float2) x 2 output rows (even/odd phase)
__global__ __launch_bounds__(256) void k_upy(const float* __restrict__ t,
    const float* __restrict__ f, float* __restrict__ out)
{
    int idx  = blockIdx.x * 256 + threadIdx.x;  // over planes*128qy*128qx
    int qx   = idx & 127;
    int rest = idx >> 7;
    int qy   = rest & 127;
    int p    = rest >> 7;                        // plane = b*3+o
    const float2* tc = reinterpret_cast<const float2*>(t + (size_t)p * H_ * OH_) + qx;
    int i0 = qy - 3;
    float2 v[7];
    #pragma unroll
    for (int j = 0; j < 7; ++j) {
        int i = i0 + j;
        v[j] = (i >= 0 && i < H_) ? tc[(size_t)i * (OH_/2)] : make_float2(0.f, 0.f);
    }
    float r0c0=0.f, r0c1=0.f, r1c0=0.f, r1c1=0.f;
    #pragma unroll
    for (int j = 0; j < 6; ++j) { float c = f[11-2*j]; r0c0 += v[j].x*c; r0c1 += v[j].y*c; }
    #pragma unroll
    for (int j = 0; j < 7; ++j) { float c = f[12-2*j]; r1c0 += v[j].x*c; r1c1 += v[j].y*c; }
    size_t rowbase = ((size_t)p * OH_ + 2*qy) * OH_ + 2*qx;
    *reinterpret_cast<float2*>(out + rowbase)       = make_float2(r0c0 * 2.f, r0c1 * 2.f);
    *reinterpret_cast<float2*>(out + rowbase + OH_) = make_float2(r1c0 * 2.f, r1c1 * 2.f);
}

extern "C" void kernel_launch(void* const* d_in, const int* in_sizes, int n_in,
                              void* d_out, int out_size, void* d_ws, size_t ws_size,
                              hipStream_t stream)
{
    const float* x  = (const float*)d_in[0];  // (16,256,128,128)
    const float* w  = (const float*)d_in[1];  // (16,512)
    const float* aw = (const float*)d_in[2];  // (256,512)
    const float* ab = (const float*)d_in[3];  // (256,)
    const float* cw = (const float*)d_in[4];  // (3,256,1,1)
    const float* cb = (const float*)d_in[5];  // (3,)
    const float* f  = (const float*)d_in[6];  // (13,)

    float* mw = (float*)d_ws;                 // 16*256*4 floats = 64 KB
    float* y  = mw + B_ * CIN_ * 4;           // 16*3*128*128 floats = 3 MB
    float* t  = y + (size_t)B_ * COUT_ * HW_; // 16*3*128*256 floats = 6 MB
    float* out = (float*)d_out;               // (16,3,256,256) fp32

    hipLaunchKernelGGL(k_styles, dim3(B_*CIN_), dim3(64),  0, stream, w, aw, ab, cw, mw);
    hipLaunchKernelGGL(k_conv,   dim3(B_*32),   dim3(256), 0, stream, x, mw, cb, y);
    hipLaunchKernelGGL(k_upx,    dim3(3072),    dim3(256), 0, stream, y, f, t);
    hipLaunchKernelGGL(k_upy,    dim3(3072),    dim3(256), 0, stream, t, f, out);
}

// Round 4
// 379.017 us; speedup vs baseline: 1.0101x; 1.0101x over previous
//
#include <hip/hip_runtime.h>
#include <hip/hip_bf16.h>

#define B_    16
#define CIN_  256
#define COUT_ 3
#define WDIM_ 512
#define H_    128
#define HW_   (H_*H_)     // 16384
#define OH_   256

// -------- Kernel 1: styles + modulated 1x1 weights --------
// mw[b][i] = float4( k[0,i]*st, k[1,i]*st, k[2,i]*st, 0 )
// st = (dot(w[b,:], aw[i,:]) / sqrt(512) + ab[i]) / 16
__global__ __launch_bounds__(64) void k_styles(const float* __restrict__ w,
    const float* __restrict__ aw, const float* __restrict__ ab,
    const float* __restrict__ cw, float* __restrict__ mw)
{
    int bi = blockIdx.x;            // b*256 + i
    int b = bi >> 8, i = bi & 255;
    int lane = threadIdx.x;
    const float* wr = w + b * WDIM_;
    const float* ar = aw + (size_t)i * WDIM_;
    float s = 0.f;
    #pragma unroll
    for (int t = 0; t < 8; ++t) s += wr[lane + 64*t] * ar[lane + 64*t];
    #pragma unroll
    for (int off = 32; off > 0; off >>= 1) s += __shfl_down(s, off);
    if (lane == 0) {
        float st = (s * 0.04419417382415922f + ab[i]) * 0.0625f; // 1/sqrt(512), 1/sqrt(256)
        float4 v;
        v.x = cw[i]          * st;
        v.y = cw[CIN_ + i]   * st;
        v.z = cw[2*CIN_ + i] * st;
        v.w = 0.f;
        reinterpret_cast<float4*>(mw)[bi] = v;
    }
}

// -------- Kernel 2: modulated 1x1 conv + bias + clamp --------
// y[b][o][hw] = clamp(sum_i x[b][i][hw]*mw[b][i][o] + cb[o], +-256)
// 256 blocks x 256 thr, 4 px/thread (float4 = 16B/lane coalesced loads)
__global__ __launch_bounds__(256) void k_conv(const float* __restrict__ x,
    const float* __restrict__ mw, const float* __restrict__ cb,
    float* __restrict__ y)
{
    int b    = blockIdx.x >> 4;                               // 16 blocks / batch
    int base = ((blockIdx.x & 15) << 10) + (threadIdx.x << 2); // 1024 px / block
    const float4* xp  = reinterpret_cast<const float4*>(x + (size_t)b * CIN_ * HW_ + base);
    const float4* mwp = reinterpret_cast<const float4*>(mw) + b * CIN_;
    float a0[4] = {0,0,0,0}, a1[4] = {0,0,0,0}, a2[4] = {0,0,0,0};
    #pragma unroll 8
    for (int i = 0; i < CIN_; ++i) {
        float4 xv = xp[(size_t)i * (HW_/4)];
        float4 m  = mwp[i];
        float xs[4] = { xv.x, xv.y, xv.z, xv.w };
        #pragma unroll
        for (int p = 0; p < 4; ++p) {
            a0[p] += xs[p]*m.x;
            a1[p] += xs[p]*m.y;
            a2[p] += xs[p]*m.z;
        }
    }
    float b0 = cb[0], b1 = cb[1], b2 = cb[2];
    auto cl = [](float v){ return fminf(fmaxf(v, -256.f), 256.f); };
    float* yp = y + (size_t)b * COUT_ * HW_ + base;
    float4 o0, o1, o2;
    o0.x=cl(a0[0]+b0); o0.y=cl(a0[1]+b0); o0.z=cl(a0[2]+b0); o0.w=cl(a0[3]+b0);
    o1.x=cl(a1[0]+b1); o1.y=cl(a1[1]+b1); o1.z=cl(a1[2]+b1); o1.w=cl(a1[3]+b1);
    o2.x=cl(a2[0]+b2); o2.y=cl(a2[1]+b2); o2.z=cl(a2[2]+b2); o2.w=cl(a2[3]+b2);
    *reinterpret_cast<float4*>(yp)          = o0;
    *reinterpret_cast<float4*>(yp +   HW_)  = o1;
    *reinterpret_cast<float4*>(yp + 2*HW_)  = o2;
}

// -------- Kernel 3: fused separable 2x polyphase upsample (13-tap) --------
// Per 2x2 output quad at (2qy.., 2qx..):
//   e_j = sum_{i=0..5} y[qy-3+j][qx-3+i]*f[11-2i],  o_j = sum_{i=0..6} ... f[12-2i]
//   out[2qy  ][2qx] = 4*sum_{j=0..5} f[11-2j]*e_j   (x2 gain per axis)
//   out[2qy  ][2qx+1] = 4*sum f[11-2j]*o_j
//   out[2qy+1][2qx]   = 4*sum_{j=0..6} f[12-2j]*e_j
//   out[2qy+1][2qx+1] = 4*sum f[12-2j]*o_j
// Block = 1 plane x 16 q-rows; LDS band 22 x 134 (cols padded with 3 zeros each side)
#define BAND_  16
#define LROWS_ 22          // BAND_ + 6
#define LCOLS_ 136         // 134 used, padded to 8B multiple
__global__ __launch_bounds__(256) void k_up(const float* __restrict__ y,
    const float* __restrict__ f, float* __restrict__ out)
{
    __shared__ float ys[LROWS_][LCOLS_];
    int p    = blockIdx.x >> 3;          // plane = b*3+o  (48)
    int q0   = (blockIdx.x & 7) * BAND_; // first q-row of band
    int tid  = threadIdx.x;

    const float* yp = y + (size_t)p * HW_;
    // stage band with halo: ys[r][c] = y[q0-3+r][c-3] (zeros outside)
    for (int e = tid; e < LROWS_ * LCOLS_; e += 256) {
        int r = e / LCOLS_, c = e - r * LCOLS_;
        int gr = q0 - 3 + r, gc = c - 3;
        float v = 0.f;
        if (gr >= 0 && gr < H_ && gc >= 0 && gc < H_) v = yp[gr * H_ + gc];
        ys[r][c] = v;
    }
    __syncthreads();

    float fe[6], fo[7];
    #pragma unroll
    for (int i = 0; i < 6; ++i) fe[i] = f[11 - 2*i];
    #pragma unroll
    for (int i = 0; i < 7; ++i) fo[i] = f[12 - 2*i];

    int qx  = tid & 127;
    int qy0 = tid >> 7;                  // 0..1
    float* outp = out + (size_t)p * OH_ * OH_;

    #pragma unroll
    for (int k = 0; k < 8; ++k) {
        int qy = qy0 + 2*k;              // 0..15 within band
        float e_[7], o_[7];
        #pragma unroll
        for (int j = 0; j < 7; ++j) {
            const float* row = &ys[qy + j][qx];   // lr = qy+j, lc = qx+i
            float e = 0.f, o = 0.f;
            #pragma unroll
            for (int i = 0; i < 6; ++i) e += row[i] * fe[i];
            #pragma unroll
            for (int i = 0; i < 7; ++i) o += row[i] * fo[i];
            e_[j] = e; o_[j] = o;
        }
        float r0e=0.f, r0o=0.f, r1e=0.f, r1o=0.f;
        #pragma unroll
        for (int j = 0; j < 6; ++j) { r0e += fe[j]*e_[j]; r0o += fe[j]*o_[j]; }
        #pragma unroll
        for (int j = 0; j < 7; ++j) { r1e += fo[j]*e_[j]; r1o += fo[j]*o_[j]; }
        int oy = 2*(q0 + qy);
        float2* d0 = reinterpret_cast<float2*>(outp + (size_t)oy * OH_) + qx;
        float2* d1 = reinterpret_cast<float2*>(outp + (size_t)(oy+1) * OH_) + qx;
        *d0 = make_float2(r0e * 4.f, r0o * 4.f);
        *d1 = make_float2(r1e * 4.f, r1o * 4.f);
    }
}

extern "C" void kernel_launch(void* const* d_in, const int* in_sizes, int n_in,
                              void* d_out, int out_size, void* d_ws, size_t ws_size,
                              hipStream_t stream)
{
    const float* x  = (const float*)d_in[0];  // (16,256,128,128)
    const float* w  = (const float*)d_in[1];  // (16,512)
    const float* aw = (const float*)d_in[2];  // (256,512)
    const float* ab = (const float*)d_in[3];  // (256,)
    const float* cw = (const float*)d_in[4];  // (3,256,1,1)
    const float* cb = (const float*)d_in[5];  // (3,)
    const float* f  = (const float*)d_in[6];  // (13,)

    float* mw = (float*)d_ws;                 // 16*256*4 floats = 64 KB
    float* y  = mw + B_ * CIN_ * 4;           // 16*3*128*128 floats = 3 MB
    float* out = (float*)d_out;               // (16,3,256,256) fp32

    hipLaunchKernelGGL(k_styles, dim3(B_*CIN_), dim3(64),  0, stream, w, aw, ab, cw, mw);
    hipLaunchKernelGGL(k_conv,   dim3(B_*16),   dim3(256), 0, stream, x, mw, cb, y);
    hipLaunchKernelGGL(k_up,     dim3(48*8),    dim3(256), 0, stream, y, f, out);
}